// Round 1
// baseline (2335.423 us; speedup 1.0000x reference)
//
#include <hip/hip_runtime.h>
#include <stdint.h>

constexpr int kS = 512;   // sequence length
constexpr int kB = 32;    // batch (only element 0 used)
constexpr int kD = 512;   // embedding dim
constexpr int kH = 512;   // hidden
constexpr int kV = 64;    // tags
constexpr int kG = 2048;  // 4*kH gate rows

// ---------------------------------------------------------------------------
// ws layout (floats):
//   X   [512][512]        @ 0         (262144)
//   G0  [2][512][2048]    @ 262144    (2097152)   layer0 input-gate preacts
//   G1  [2][512][2048]    @ 2359296   (2097152)
//   H0  [2][512][512]     @ 4456448   (524288)    sentinel-initialized
//   H1  [2][512][512]     @ 4980736   (524288)
//   LOG [512][64]         @ 5505024   (32768)
// total 5537792 floats = 22.2 MB
// ---------------------------------------------------------------------------

__global__ __launch_bounds__(128) void k_embed(const int* __restrict__ src,
                                               const float* __restrict__ emb,
                                               float* __restrict__ X) {
  const int t = blockIdx.x;
  const int s = src[t * kB];  // batch 0 token
  const float4* e = (const float4*)(emb + (size_t)s * kD);
  float4* x = (float4*)(X + (size_t)t * kD);
  x[threadIdx.x] = e[threadIdx.x];
}

// C[d][m][n] = sum_k A[m][k] * Wih[d][n][k] + bih[d][n] + bhh[d][n]
// A[m][k] = (k<512) ? A0[m*512+k] : A1[m*512+k-512]   (concat for layer 1)
__global__ __launch_bounds__(256) void k_gemm(const float* __restrict__ A0,
                                              const float* __restrict__ A1,
                                              const float* __restrict__ Wih,
                                              const float* __restrict__ bih,
                                              const float* __restrict__ bhh,
                                              float* __restrict__ C, int K) {
  __shared__ float As[16][68];  // [k][m], padded
  __shared__ float Bs[16][68];  // [k][n]
  const int d = blockIdx.z;
  const int m0 = blockIdx.y * 64, n0 = blockIdx.x * 64;
  const float* W = Wih + (size_t)d * kG * K;
  const int tid = threadIdx.x;
  const int lr = tid >> 2, lq = tid & 3;
  const int tx = tid & 15, ty = tid >> 4;
  float acc[4][4] = {};
  for (int kb = 0; kb < K; kb += 16) {
    const int k = kb + lq * 4;
    const float* ap = (k < 512) ? (A0 + (size_t)(m0 + lr) * 512 + k)
                                : (A1 + (size_t)(m0 + lr) * 512 + (k - 512));
    const float4 va = *(const float4*)ap;
    const float4 vb = *(const float4*)(W + (size_t)(n0 + lr) * K + k);
    As[lq * 4 + 0][lr] = va.x; As[lq * 4 + 1][lr] = va.y;
    As[lq * 4 + 2][lr] = va.z; As[lq * 4 + 3][lr] = va.w;
    Bs[lq * 4 + 0][lr] = vb.x; Bs[lq * 4 + 1][lr] = vb.y;
    Bs[lq * 4 + 2][lr] = vb.z; Bs[lq * 4 + 3][lr] = vb.w;
    __syncthreads();
#pragma unroll
    for (int kk = 0; kk < 16; kk++) {
      const float4 av = *(const float4*)&As[kk][tx * 4];
      const float4 bv = *(const float4*)&Bs[kk][ty * 4];
      const float a[4] = {av.x, av.y, av.z, av.w};
      const float b[4] = {bv.x, bv.y, bv.z, bv.w};
#pragma unroll
      for (int i = 0; i < 4; i++)
#pragma unroll
        for (int j = 0; j < 4; j++) acc[i][j] += a[i] * b[j];
    }
    __syncthreads();
  }
  float bs[4];
#pragma unroll
  for (int j = 0; j < 4; j++) {
    const int n = n0 + ty * 4 + j;
    bs[j] = bih[d * kG + n] + bhh[d * kG + n];
  }
#pragma unroll
  for (int i = 0; i < 4; i++) {
    const int m = m0 + tx * 4 + i;
    float4 o;
    o.x = acc[i][0] + bs[0]; o.y = acc[i][1] + bs[1];
    o.z = acc[i][2] + bs[2]; o.w = acc[i][3] + bs[3];
    *(float4*)&C[((size_t)d * kS + m) * kG + n0 + ty * 4] = o;
  }
}

// Recurrence: grid = 32 blocks (dir = bx&1, wg = bx>>1 of 16), 512 threads.
// Each wg owns h elements [wg*32, wg*32+32) -> 128 gate rows (4 gates x 32).
// Whh slice in VGPRs: lane l of wave wv holds rows {l, l+64} x k[wv*64..+64).
// h handoff between wgs: value IS the flag (sentinel = 0xFFFFFFFF = NaN),
// relaxed agent-scope atomics -> single L3 round-trip, no fences needed.
__global__ __launch_bounds__(512) void k_rec(const float* __restrict__ Gin,
                                             const float* __restrict__ Whh,
                                             float* __restrict__ Hout) {
  __shared__ float hlds[512];
  __shared__ float part[8 * 128];
  __shared__ float cst[32];
  const int bx = blockIdx.x;
  const int dir = bx & 1, wg = bx >> 1;
  const int tid = threadIdx.x;
  const int wv = tid >> 6, l = tid & 63;
  const float* Wb = Whh + (size_t)dir * kG * kH;
  const float* Gb = Gin + (size_t)dir * kS * kG;
  float* Hb = Hout + (size_t)dir * kS * kH;

  float4 w0[16], w1[16];
  {
    int lr = l;
    int grow = ((lr >> 5) << 9) + wg * 32 + (lr & 31);
    const float4* p = (const float4*)(Wb + (size_t)grow * kH + wv * 64);
#pragma unroll
    for (int i = 0; i < 16; i++) w0[i] = p[i];
    lr = l + 64;
    grow = ((lr >> 5) << 9) + wg * 32 + (lr & 31);
    p = (const float4*)(Wb + (size_t)grow * kH + wv * 64);
#pragma unroll
    for (int i = 0; i < 16; i++) w1[i] = p[i];
  }
  if (tid < 32) cst[tid] = 0.0f;

  for (int s = 0; s < kS; s++) {
    const int t = dir ? (kS - 1 - s) : s;
    float g0 = 0.f, g1 = 0.f, g2 = 0.f, g3 = 0.f;
    if (tid < 32) {  // prefetch gate preacts (independent of h, hides spin)
      const float* gp = Gb + (size_t)t * kG + wg * 32 + tid;
      g0 = gp[0]; g1 = gp[512]; g2 = gp[1024]; g3 = gp[1536];
    }
    if (s == 0) {
      hlds[tid] = 0.0f;
    } else {
      const int tp = dir ? (t + 1) : (t - 1);
      unsigned* hp = (unsigned*)(Hb + (size_t)tp * kH);
      unsigned u;
      do {
        u = __hip_atomic_load(hp + tid, __ATOMIC_RELAXED, __HIP_MEMORY_SCOPE_AGENT);
      } while (u == 0xFFFFFFFFu);
      hlds[tid] = __uint_as_float(u);
    }
    __syncthreads();
    float a0x = 0, a0y = 0, a0z = 0, a0w = 0;
    float a1x = 0, a1y = 0, a1z = 0, a1w = 0;
#pragma unroll
    for (int kb = 0; kb < 16; kb++) {
      const float4 hv = *(const float4*)&hlds[wv * 64 + kb * 4];  // broadcast
      a0x += w0[kb].x * hv.x; a0y += w0[kb].y * hv.y;
      a0z += w0[kb].z * hv.z; a0w += w0[kb].w * hv.w;
      a1x += w1[kb].x * hv.x; a1y += w1[kb].y * hv.y;
      a1z += w1[kb].z * hv.z; a1w += w1[kb].w * hv.w;
    }
    part[wv * 128 + l] = (a0x + a0y) + (a0z + a0w);
    part[wv * 128 + 64 + l] = (a1x + a1y) + (a1z + a1w);
    __syncthreads();
    if (tid < 32) {
      float si = g0, sf = g1, sg = g2, so = g3;
#pragma unroll
      for (int w = 0; w < 8; w++) {
        si += part[w * 128 + tid];
        sf += part[w * 128 + 32 + tid];
        sg += part[w * 128 + 64 + tid];
        so += part[w * 128 + 96 + tid];
      }
      float c = cst[tid];
      const float ig = 1.0f / (1.0f + expf(-si));
      const float fg = 1.0f / (1.0f + expf(-sf));
      const float og = 1.0f / (1.0f + expf(-so));
      c = fg * c + ig * tanhf(sg);
      const float h = og * tanhf(c);
      cst[tid] = c;
      __hip_atomic_store((unsigned*)(Hb + (size_t)t * kH) + wg * 32 + tid,
                         __float_as_uint(h), __ATOMIC_RELAXED,
                         __HIP_MEMORY_SCOPE_AGENT);
    }
    // no 3rd sync needed: next-iter hlds writes only touch hlds (all threads
    // passed the part[] sync), cell threads re-sync at next iteration top.
  }
}

__global__ __launch_bounds__(256) void k_logits(const float* __restrict__ H1,
                                                const float* __restrict__ Wout,
                                                const float* __restrict__ bout,
                                                float* __restrict__ LOG) {
  __shared__ float hl[1024];
  const int t = blockIdx.x;
  const int tid = threadIdx.x;
  float4* hl4 = (float4*)hl;
  if (tid < 128)
    hl4[tid] = ((const float4*)(H1 + (size_t)t * kH))[tid];
  else
    hl4[tid] = ((const float4*)(H1 + (size_t)(kS + t) * kH))[tid - 128];
  __syncthreads();
  const int v = tid >> 2, q = tid & 3;
  const float4* w4 = (const float4*)(Wout + (size_t)v * 1024);
  float4 a = {0, 0, 0, 0};
#pragma unroll 8
  for (int j = 0; j < 64; j++) {
    const int idx = j * 4 + q;  // interleave q -> contiguous 64B per v
    const float4 w = w4[idx];
    const float4 x = hl4[idx];
    a.x += w.x * x.x; a.y += w.y * x.y; a.z += w.z * x.z; a.w += w.w * x.w;
  }
  float acc = (a.x + a.y) + (a.z + a.w);
  acc += __shfl_xor(acc, 1);
  acc += __shfl_xor(acc, 2);
  if (q == 0) LOG[(size_t)t * kV + v] = acc + bout[v];
}

__global__ __launch_bounds__(256) void k_viterbi(const float* __restrict__ LOG,
                                                 const float* __restrict__ trans,
                                                 int* __restrict__ out) {
  __shared__ float delta[64];
  __shared__ float redS[4 * 64];
  __shared__ int redA[4 * 64];
  __shared__ unsigned char bp[511 * 64];
  const int tid = threadIdx.x;
  const int c = tid & 63, q = tid >> 6;
  if (tid < 64) delta[tid] = LOG[tid];
  __syncthreads();
  for (int t = 1; t < kS; t++) {
    float best = -1e30f;
    int bi = 0;
#pragma unroll 4
    for (int pp = 0; pp < 16; pp++) {
      const int p = q * 16 + pp;
      const float sc = delta[p] + trans[p * 64 + c];
      if (sc > best) { best = sc; bi = p; }  // strict > == first-max (numpy)
    }
    redS[q * 64 + c] = best;
    redA[q * 64 + c] = bi;
    __syncthreads();
    if (tid < 64) {
      float b = redS[c];
      int a = redA[c];
      for (int qq = 1; qq < 4; qq++) {  // ascending q keeps first-max ties
        const float v2 = redS[qq * 64 + c];
        if (v2 > b) { b = v2; a = redA[qq * 64 + c]; }
      }
      bp[(t - 1) * 64 + c] = (unsigned char)a;
      delta[c] = b + LOG[t * 64 + c];
    }
    __syncthreads();
  }
  if (tid == 0) {
    float b = delta[0];
    int a = 0;
    for (int i = 1; i < 64; i++)
      if (delta[i] > b) { b = delta[i]; a = i; }
    int idx = a;
    out[kS - 1] = idx;
    for (int t = kS - 2; t >= 0; t--) {
      idx = bp[t * 64 + idx];
      out[t] = idx;
    }
  }
}

extern "C" void kernel_launch(void* const* d_in, const int* in_sizes, int n_in,
                              void* d_out, int out_size, void* d_ws,
                              size_t ws_size, hipStream_t stream) {
  (void)in_sizes; (void)n_in; (void)out_size; (void)ws_size;
  const int* source  = (const int*)d_in[0];
  // d_in[1] = target (unused by reference forward path)
  const float* emb   = (const float*)d_in[2];
  const float* Wih0  = (const float*)d_in[3];
  const float* Whh0  = (const float*)d_in[4];
  const float* bih0  = (const float*)d_in[5];
  const float* bhh0  = (const float*)d_in[6];
  const float* Wih1  = (const float*)d_in[7];
  const float* Whh1  = (const float*)d_in[8];
  const float* bih1  = (const float*)d_in[9];
  const float* bhh1  = (const float*)d_in[10];
  const float* Wout  = (const float*)d_in[11];
  const float* bout  = (const float*)d_in[12];
  const float* trans = (const float*)d_in[13];

  float* ws = (float*)d_ws;
  float* X   = ws;
  float* G0  = ws + 262144;
  float* G1  = ws + 2359296;
  float* H0  = ws + 4456448;
  float* H1  = ws + 4980736;
  float* LOG = ws + 5505024;

  // sentinel-init H0|H1 (contiguous 4 MB): 0xFFFFFFFF == NaN, can never be a
  // computed h (|h| < 1), so "data is the flag" for the spin handoff.
  hipMemsetAsync(H0, 0xFF, (size_t)(524288 + 524288) * sizeof(float), stream);

  k_embed<<<kS, 128, 0, stream>>>(source, emb, X);

  dim3 gg(32, 8, 2);  // N/64, M/64, dirs
  k_gemm<<<gg, 256, 0, stream>>>(X, X, Wih0, bih0, bhh0, G0, 512);
  k_rec<<<32, 512, 0, stream>>>(G0, Whh0, H0);
  k_gemm<<<gg, 256, 0, stream>>>(H0, H0 + 262144, Wih1, bih1, bhh1, G1, 1024);
  k_rec<<<32, 512, 0, stream>>>(G1, Whh1, H1);
  k_logits<<<kS, 256, 0, stream>>>(H1, Wout, bout, LOG);
  k_viterbi<<<1, 256, 0, stream>>>(LOG, trans, (int*)d_out);
}